// Round 5
// baseline (533.756 us; speedup 1.0000x reference)
//
#include <hip/hip_runtime.h>

// GraphConvolution: out = segment_sum(edge_val * x[edge_col], edge_row) + x_0 + bias
// (Cayley transform in the reference is exactly identity => support == x.)
//
// Round 5: XCD-sharded binning + LDS-accumulated aggregation.
//   Phase 1: entry = (row_in_bin << 26) | edge_id appended to bucket[bin][xcc].
//            Sharding by hardware XCC_ID keeps each append frontier owned by
//            one XCD's L2 -> writes temporally coalesce (no 64B/4B blowup).
//   Phase 2: one block per 64-row bin, 16KB LDS f32 accumulator (ds_add_f32),
//            wave-batched entry loads, coalesced 256B x-row gathers,
//            epilogue out += accum (out pre-initialized to x0 + bias).
//   Tiers for capacity overflow: shard bucket -> overflow list (drained by a
//   post-pass atomic kernel) -> direct atomics. Correct at any capacity.

#define DFEAT 64
#define RPB   64            // rows per bin (rin = 6 bits)
#define NSH   8             // shards per bin (one per XCD)
#define CUR_PAD 16          // cursor padding: 16 ints = 64 B line

__device__ __forceinline__ unsigned get_xcc_id() {
    unsigned v;
    asm volatile("s_getreg_b32 %0, hwreg(HW_REG_XCC_ID, 0, 32)" : "=s"(v));
    return v & 7u;
}

// out = x_0 + bias  (vectorized float4; D=64 divisible by 4 so no bias wrap)
__global__ void init_out_kernel(const float* __restrict__ x0,
                                const float* __restrict__ bias,
                                float* __restrict__ out, int n4) {
    int i = blockIdx.x * blockDim.x + threadIdx.x;
    if (i < n4) {
        float4 v = ((const float4*)x0)[i];
        int d = (i * 4) & (DFEAT - 1);
        v.x += bias[d + 0]; v.y += bias[d + 1];
        v.z += bias[d + 2]; v.w += bias[d + 3];
        ((float4*)out)[i] = v;
    }
}

// Phase 1: bin+shard scatter of 4B packed entries. Reads only edge_row.
__global__ void bin_scatter_kernel(const int* __restrict__ edge_row,
                                   const int* __restrict__ edge_col,
                                   const float* __restrict__ edge_val,
                                   const float* __restrict__ x,
                                   int* __restrict__ cursors,
                                   unsigned* __restrict__ entries,
                                   int* __restrict__ ov_cursor,
                                   int* __restrict__ ov_list,
                                   float* __restrict__ out,
                                   int E, int cap, int ov_cap) {
    unsigned xcc = get_xcc_id();
    int i = blockIdx.x * blockDim.x + threadIdx.x;
    int stride = gridDim.x * blockDim.x;
    for (int e = i; e < E; e += stride) {
        int r = edge_row[e];
        int b = r >> 6;                       // bin = row / RPB
        int sidx = b * NSH + (int)xcc;
        int pos = atomicAdd(&cursors[sidx * CUR_PAD], 1);
        if (pos < cap) {
            entries[(size_t)sidx * cap + pos] =
                ((unsigned)(r & (RPB - 1)) << 26) | (unsigned)e;
        } else {
            int op = atomicAdd(ov_cursor, 1);
            if (op < ov_cap) {
                ov_list[op] = e;
            } else {
                // last-resort direct accumulate (out already = x0 + bias)
                int c = edge_col[e];
                float v = edge_val[e];
                for (int d = 0; d < DFEAT; d++)
                    atomicAdd(&out[(size_t)r * DFEAT + d],
                              v * x[(size_t)c * DFEAT + d]);
            }
        }
    }
}

// Phase 2: one block per bin; LDS accumulate; out += accum.
__global__ __launch_bounds__(256) void bin_aggregate_kernel(
        const float* __restrict__ x,
        const int* __restrict__ edge_col,
        const float* __restrict__ edge_val,
        const int* __restrict__ cursors,
        const unsigned* __restrict__ entries,
        float* __restrict__ out, int N, int cap) {
    __shared__ float accum[RPB * DFEAT];      // 16 KB
    int b = blockIdx.x;
    int t = threadIdx.x;

    float4* a4 = (float4*)accum;
    for (int i = t; i < RPB * DFEAT / 4; i += 256)
        a4[i] = make_float4(0.f, 0.f, 0.f, 0.f);
    __syncthreads();

    int wave = t >> 6, lane = t & 63;
    for (int sh = wave; sh < NSH; sh += 4) {
        int sidx = b * NSH + sh;
        int cnt = cursors[sidx * CUR_PAD];
        if (cnt > cap) cnt = cap;
        const unsigned* list = entries + (size_t)sidx * cap;
        for (int s0 = 0; s0 < cnt; s0 += 64) {
            int m = cnt - s0; if (m > 64) m = 64;
            unsigned ent = 0; int c = 0; float v = 0.f;
            if (lane < m) {
                ent = list[s0 + lane];
                int eid = (int)(ent & 0x03FFFFFFu);
                c = edge_col[eid];
                v = edge_val[eid];
            }
            int rin = (int)(ent >> 26);
            #pragma unroll 4
            for (int j = 0; j < m; j++) {
                int   cj = __shfl(c, j);
                float vj = __shfl(v, j);
                int   rj = __shfl(rin, j);
                float xv = x[(size_t)cj * DFEAT + lane];
                atomicAdd(&accum[rj * DFEAT + lane], vj * xv);  // ds_add_f32
            }
        }
    }
    __syncthreads();

    // epilogue: out[rows of bin] += accum   (out was pre-set to x0 + bias)
    int rlo = b * RPB;
    int nrow = N - rlo; if (nrow > RPB) nrow = RPB;
    int n4 = nrow * DFEAT / 4;
    float4* o4 = (float4*)(out + (size_t)rlo * DFEAT);
    const float4* acc4 = (const float4*)accum;
    for (int i = t; i < n4; i += 256) {
        float4 ov = o4[i], av = acc4[i];
        ov.x += av.x; ov.y += av.y; ov.z += av.z; ov.w += av.w;
        o4[i] = ov;
    }
}

// Phase 3: drain overflow list (normally empty) with direct atomics.
__global__ void overflow_drain_kernel(const int* __restrict__ edge_row,
                                      const int* __restrict__ edge_col,
                                      const float* __restrict__ edge_val,
                                      const float* __restrict__ x,
                                      const int* __restrict__ ov_cursor,
                                      const int* __restrict__ ov_list,
                                      float* __restrict__ out, int ov_cap) {
    int n = ov_cursor[0];
    if (n > ov_cap) n = ov_cap;
    int wid = (blockIdx.x * blockDim.x + threadIdx.x) >> 6;
    int lane = threadIdx.x & 63;
    int nw = (gridDim.x * blockDim.x) >> 6;
    for (int k = wid; k < n; k += nw) {
        int e = ov_list[k];
        int r = edge_row[e], c = edge_col[e];
        float v = edge_val[e];
        atomicAdd(&out[(size_t)r * DFEAT + lane],
                  v * x[(size_t)c * DFEAT + lane]);
    }
}

// ---------- fallback path (round-1 atomic scatter) ----------
__global__ void edge_scatter_kernel(const float* __restrict__ x,
                                    const float* __restrict__ edge_val,
                                    const int* __restrict__ edge_row,
                                    const int* __restrict__ edge_col,
                                    float* __restrict__ out, int E) {
    int tid = blockIdx.x * blockDim.x + threadIdx.x;
    int wave = tid >> 6, lane = tid & 63;
    int nwaves = (gridDim.x * blockDim.x) >> 6;
    for (int e = wave; e < E; e += nwaves) {
        int row = edge_row[e];
        int col = edge_col[e];
        float val = edge_val[e];
        atomicAdd(&out[row * DFEAT + lane], val * x[col * DFEAT + lane]);
    }
}

extern "C" void kernel_launch(void* const* d_in, const int* in_sizes, int n_in,
                              void* d_out, int out_size, void* d_ws, size_t ws_size,
                              hipStream_t stream) {
    const float* x    = (const float*)d_in[0];
    const float* x0   = (const float*)d_in[1];
    const float* ev   = (const float*)d_in[2];
    // d_in[3] = weight: unused (Cayley == identity)
    const float* bias = (const float*)d_in[4];
    const int*   er   = (const int*)d_in[5];
    const int*   ec   = (const int*)d_in[6];
    float* out = (float*)d_out;

    int E = in_sizes[2];
    int N = out_size / DFEAT;
    int n4 = out_size / 4;

    int NB = (N + RPB - 1) / RPB;             // 1024 bins for N=65536
    long long NS = (long long)NB * NSH;       // shard lists

    // workspace layout: [cursors NS*64B][ov_cursor 256B][ov_list][entries]
    size_t cursor_bytes = (size_t)NS * CUR_PAD * 4;
    size_t ovc_bytes    = 256;
    int    ov_cap       = 131072;
    size_t ov_bytes     = ((size_t)ov_cap * 4 + 255) & ~size_t(255);
    size_t fixed        = cursor_bytes + ovc_bytes + ov_bytes;

    long long cap = 0;
    if (ws_size > fixed)
        cap = (long long)((ws_size - fixed) / ((size_t)NS * 4));
    if (cap > 4096) cap = 4096;

    // out = x0 + bias first in all paths.
    init_out_kernel<<<(n4 + 255) / 256, 256, 0, stream>>>(x0, bias, out, n4);

    if (cap >= 32 && E < (1 << 26)) {
        char* ws = (char*)d_ws;
        int*      cursors = (int*)ws;
        int*      ovc     = (int*)(ws + cursor_bytes);
        int*      ov_list = (int*)(ws + cursor_bytes + ovc_bytes);
        unsigned* entries = (unsigned*)(ws + fixed);

        hipMemsetAsync(cursors, 0, cursor_bytes + ovc_bytes, stream);
        bin_scatter_kernel<<<2048, 256, 0, stream>>>(er, ec, ev, x, cursors,
                                                     entries, ovc, ov_list, out,
                                                     E, (int)cap, ov_cap);
        bin_aggregate_kernel<<<NB, 256, 0, stream>>>(x, ec, ev, cursors,
                                                     entries, out, N, (int)cap);
        overflow_drain_kernel<<<64, 256, 0, stream>>>(er, ec, ev, x, ovc,
                                                      ov_list, out, ov_cap);
    } else {
        // workspace too small / E too large: atomic-scatter fallback
        edge_scatter_kernel<<<8192, 256, 0, stream>>>(x, ev, er, ec, out, E);
    }
}

// Round 6
// 488.966 us; speedup vs baseline: 1.0916x; 1.0916x over previous
//
#include <hip/hip_runtime.h>

// GraphConvolution: out = segment_sum(edge_val * x[edge_col], edge_row) + x_0 + bias
// (Cayley transform in the reference is exactly identity => support == x.)
//
// Round 6: XCD-sharded binning with FULL PAYLOAD entries + high-MLP aggregate.
//   Phase 1 (bin_scatter): entry = int2{(row_in_bin<<26)|col, val} appended to
//     shard (bin, hw XCC_ID). Sharding keeps each append frontier in one
//     XCD's L2 so the 8B random stores temporally coalesce.
//   Phase 2 (bin_aggregate): 1024 blocks x 8 waves (one wave per shard),
//     all 8192 waves resident. Entries read sequentially (no random id
//     gathers). Inner loop: groups of 8 edges, readlane broadcast, 8
//     independent 256B x-row gathers in flight, then 8 ds_add_f32 into a
//     16KB LDS accumulator. Epilogue: out = x0 + bias + accum (pure store).
//   Overflow: shard cap exceeded -> ov_list (capacity E, cannot overflow)
//     drained after aggregate with atomics. Correct for any cap.

#define DFEAT 64
#define RPB   64            // rows per bin (rin = 6 bits)
#define NSH   8             // shards per bin (one per XCD)
#define CUR_PAD 16          // cursor padding: 16 ints = 64 B line
#define AGG_THREADS 512     // 8 waves = one per shard

__device__ __forceinline__ unsigned get_xcc_id() {
    unsigned v;
    asm volatile("s_getreg_b32 %0, hwreg(HW_REG_XCC_ID, 0, 32)" : "=s"(v));
    return v & 7u;
}

// Phase 1: one thread per edge; append full payload to (bin, xcc) shard.
__global__ void bin_scatter_kernel(const int* __restrict__ edge_row,
                                   const int* __restrict__ edge_col,
                                   const float* __restrict__ edge_val,
                                   int* __restrict__ cursors,
                                   int2* __restrict__ entries,
                                   int* __restrict__ ov_cursor,
                                   int* __restrict__ ov_list,
                                   int E, int cap) {
    int e = blockIdx.x * blockDim.x + threadIdx.x;
    if (e >= E) return;
    int r = edge_row[e];
    int b = r >> 6;                           // bin = row / RPB
    int sidx = b * NSH + (int)get_xcc_id();
    int pos = atomicAdd(&cursors[sidx * CUR_PAD], 1);
    if (pos < cap) {
        int2 ent;
        ent.x = ((r & (RPB - 1)) << 26) | edge_col[e];
        ent.y = __float_as_int(edge_val[e]);
        entries[(size_t)sidx * cap + pos] = ent;
    } else {
        int op = atomicAdd(ov_cursor, 1);
        ov_list[op] = e;                      // ov capacity == E: can't overflow
    }
}

// Phase 2: one block per bin, one wave per shard, LDS accumulate,
// epilogue out = x0 + bias + accum.
__global__ __launch_bounds__(AGG_THREADS) void bin_aggregate_kernel(
        const float* __restrict__ x,
        const float* __restrict__ x0,
        const float* __restrict__ bias,
        const int* __restrict__ cursors,
        const int2* __restrict__ entries,
        float* __restrict__ out, int N, int cap) {
    __shared__ float accum[RPB * DFEAT];      // 16 KB
    int b = blockIdx.x;
    int t = threadIdx.x;

    float4* a4 = (float4*)accum;
    for (int i = t; i < RPB * DFEAT / 4; i += AGG_THREADS)
        a4[i] = make_float4(0.f, 0.f, 0.f, 0.f);
    __syncthreads();

    int wave = t >> 6, lane = t & 63;
    int sidx = b * NSH + wave;
    int cnt = cursors[sidx * CUR_PAD];
    if (cnt > cap) cnt = cap;
    const int2* list = entries + (size_t)sidx * cap;

    for (int s0 = 0; s0 < cnt; s0 += 64) {
        int m = cnt - s0; if (m > 64) m = 64;
        int pc = 0; float pv = 0.f;           // padding lanes: col 0, val 0
        if (lane < m) {
            int2 p = list[s0 + lane];
            pc = p.x;
            pv = __int_as_float(p.y);
        }
        for (int j0 = 0; j0 < m; j0 += 8) {
            float xv[8], vv[8];
            int   rr[8];
            #pragma unroll
            for (int k = 0; k < 8; k++) {
                int   cj = __builtin_amdgcn_readlane(pc, j0 + k);
                int   vb = __builtin_amdgcn_readlane(__float_as_int(pv), j0 + k);
                rr[k] = ((unsigned)cj) >> 26;
                vv[k] = __int_as_float(vb);
                xv[k] = x[(size_t)(cj & 0x03FFFFFF) * DFEAT + lane];
            }
            #pragma unroll
            for (int k = 0; k < 8; k++)
                atomicAdd(&accum[rr[k] * DFEAT + lane], vv[k] * xv[k]);
        }
    }
    __syncthreads();

    // epilogue: out = x0 + bias + accum (pure store; bins cover rows exactly)
    int rlo = b * RPB;
    int nrow = N - rlo; if (nrow > RPB) nrow = RPB;
    int n4 = nrow * DFEAT / 4;
    const float4* x04 = (const float4*)(x0 + (size_t)rlo * DFEAT);
    float4* o4 = (float4*)(out + (size_t)rlo * DFEAT);
    for (int i = t; i < n4; i += AGG_THREADS) {
        float4 v = x04[i], a = a4[i];
        int d = (i * 4) & (DFEAT - 1);
        v.x += a.x + bias[d + 0];
        v.y += a.y + bias[d + 1];
        v.z += a.z + bias[d + 2];
        v.w += a.w + bias[d + 3];
        o4[i] = v;
    }
}

// Phase 3: drain overflow list (normally empty). Runs AFTER aggregate.
__global__ void overflow_drain_kernel(const int* __restrict__ edge_row,
                                      const int* __restrict__ edge_col,
                                      const float* __restrict__ edge_val,
                                      const float* __restrict__ x,
                                      const int* __restrict__ ov_cursor,
                                      const int* __restrict__ ov_list,
                                      float* __restrict__ out, int E) {
    int n = ov_cursor[0];
    if (n > E) n = E;
    int wid = (blockIdx.x * blockDim.x + threadIdx.x) >> 6;
    int lane = threadIdx.x & 63;
    int nw = (gridDim.x * blockDim.x) >> 6;
    for (int k = wid; k < n; k += nw) {
        int e = ov_list[k];
        int r = edge_row[e], c = edge_col[e];
        float v = edge_val[e];
        atomicAdd(&out[(size_t)r * DFEAT + lane],
                  v * x[(size_t)c * DFEAT + lane]);
    }
}

// ---------- fallback path (round-1 structure; used only if ws too small) ----------
__global__ void init_out_kernel(const float* __restrict__ x0,
                                const float* __restrict__ bias,
                                float* __restrict__ out, int n4) {
    int i = blockIdx.x * blockDim.x + threadIdx.x;
    if (i < n4) {
        float4 v = ((const float4*)x0)[i];
        int d = (i * 4) & (DFEAT - 1);
        v.x += bias[d + 0]; v.y += bias[d + 1];
        v.z += bias[d + 2]; v.w += bias[d + 3];
        ((float4*)out)[i] = v;
    }
}

__global__ void edge_scatter_kernel(const float* __restrict__ x,
                                    const float* __restrict__ edge_val,
                                    const int* __restrict__ edge_row,
                                    const int* __restrict__ edge_col,
                                    float* __restrict__ out, int E) {
    int tid = blockIdx.x * blockDim.x + threadIdx.x;
    int wave = tid >> 6, lane = tid & 63;
    int nwaves = (gridDim.x * blockDim.x) >> 6;
    for (int e = wave; e < E; e += nwaves) {
        int row = edge_row[e];
        int col = edge_col[e];
        float val = edge_val[e];
        atomicAdd(&out[row * DFEAT + lane], val * x[col * DFEAT + lane]);
    }
}

extern "C" void kernel_launch(void* const* d_in, const int* in_sizes, int n_in,
                              void* d_out, int out_size, void* d_ws, size_t ws_size,
                              hipStream_t stream) {
    const float* x    = (const float*)d_in[0];
    const float* x0   = (const float*)d_in[1];
    const float* ev   = (const float*)d_in[2];
    // d_in[3] = weight: unused (Cayley == identity)
    const float* bias = (const float*)d_in[4];
    const int*   er   = (const int*)d_in[5];
    const int*   ec   = (const int*)d_in[6];
    float* out = (float*)d_out;

    int E = in_sizes[2];
    int N = out_size / DFEAT;

    int NB = (N + RPB - 1) / RPB;             // bins (1024 for N=65536)
    long long NS = (long long)NB * NSH;       // shard count

    // workspace layout: [cursors][ov_cursor][ov_list(E)][entries]
    size_t cur_bytes = (((size_t)NS * CUR_PAD * 4) + 255) & ~size_t(255);
    size_t ovc_bytes = 256;
    size_t ov_bytes  = (((size_t)E * 4) + 255) & ~size_t(255);
    size_t fixed     = cur_bytes + ovc_bytes + ov_bytes;

    long long cap = 0;
    if (ws_size > fixed)
        cap = (long long)((ws_size - fixed) / ((size_t)NS * 8));
    if (cap > 2048) cap = 2048;

    if (cap >= 48 && N < (1 << 26) && N % RPB == 0) {
        char* ws = (char*)d_ws;
        int*  cursors = (int*)ws;
        int*  ovc     = (int*)(ws + cur_bytes);
        int*  ov_list = (int*)(ws + cur_bytes + ovc_bytes);
        int2* entries = (int2*)(ws + fixed);

        hipMemsetAsync(cursors, 0, cur_bytes + ovc_bytes, stream);
        bin_scatter_kernel<<<(E + 255) / 256, 256, 0, stream>>>(
            er, ec, ev, cursors, entries, ovc, ov_list, E, (int)cap);
        bin_aggregate_kernel<<<NB, AGG_THREADS, 0, stream>>>(
            x, x0, bias, cursors, entries, out, N, (int)cap);
        overflow_drain_kernel<<<64, 256, 0, stream>>>(
            er, ec, ev, x, ovc, ov_list, out, E);
    } else {
        // fallback: atomic-scatter path (correct at any ws)
        int n4 = out_size / 4;
        init_out_kernel<<<(n4 + 255) / 256, 256, 0, stream>>>(x0, bias, out, n4);
        edge_scatter_kernel<<<8192, 256, 0, stream>>>(x, ev, er, ec, out, E);
    }
}

// Round 7
// 189.944 us; speedup vs baseline: 2.8101x; 2.5743x over previous
//
#include <hip/hip_runtime.h>

// GraphConvolution: out = segment_sum(edge_val * x[edge_col], edge_row) + x_0 + bias
// (Cayley transform in the reference is exactly identity => support == x.)
//
// Round 7: R4 bucket pipeline + payload buckets + high-MLP register spmm.
//   - bucket entry = int2{col, val}: random-store write-back is line-granular
//     (64B/edge) so the 8B payload costs the same as a 4B edge id, and spmm
//     loses its two random 4B gathers per edge.
//   - spmm: one wave per row, groups of 8 readlane-broadcast edges, 8
//     independent coalesced 256B x-row gathers in flight, FMA into a REGISTER
//     accumulator. No LDS atomics anywhere (suspected CAS-loop poison in R5/R6).
//   - epilogue fused: out = acc + x0 + bias (init kernel deleted).
//   - overflow edges -> ov_list (capacity E, cannot drop), drained after spmm
//     with global HW f32 atomics. Correct for any bucket capacity.

#define DFEAT 64

// Phase 1: one thread per edge; claim slot in row bucket, store payload.
__global__ void bucket_scatter_kernel(const int* __restrict__ edge_row,
                                      const int* __restrict__ edge_col,
                                      const float* __restrict__ edge_val,
                                      int* __restrict__ cursor,
                                      int2* __restrict__ bucket,
                                      int* __restrict__ ov_cursor,
                                      int* __restrict__ ov_list,
                                      int E, int C) {
    int e = blockIdx.x * blockDim.x + threadIdx.x;
    if (e >= E) return;
    int r = edge_row[e];
    int pos = atomicAdd(&cursor[r], 1);
    if (pos < C) {
        int2 ent;
        ent.x = edge_col[e];
        ent.y = __float_as_int(edge_val[e]);
        bucket[(size_t)r * C + pos] = ent;
    } else {
        int op = atomicAdd(ov_cursor, 1);
        ov_list[op] = e;               // capacity E: cannot overflow
    }
}

// Phase 2: one 64-lane wave per row; lane d owns feature d.
// Register accumulator; 8 independent gathers in flight per group.
__global__ __launch_bounds__(256) void spmm_kernel(
        const float* __restrict__ x,
        const float* __restrict__ x0,
        const float* __restrict__ bias,
        const int* __restrict__ cursor,
        const int2* __restrict__ bucket,
        float* __restrict__ out, int n, int C) {
    int wid = (blockIdx.x * blockDim.x + threadIdx.x) >> 6;
    int lane = threadIdx.x & 63;
    if (wid >= n) return;
    int cnt = cursor[wid];
    if (cnt > C) cnt = C;              // overflow edges handled by drain pass
    const int2* bk = bucket + (size_t)wid * C;
    float acc = 0.f;
    for (int s0 = 0; s0 < cnt; s0 += 64) {
        int m = cnt - s0; if (m > 64) m = 64;
        int c = 0; float v = 0.f;      // padding lanes: col 0, val 0 -> adds 0
        if (lane < m) {
            int2 p = bk[s0 + lane];    // coalesced: row bucket is contiguous
            c = p.x;
            v = __int_as_float(p.y);
        }
        for (int j0 = 0; j0 < m; j0 += 8) {
            float xv[8], vv[8];
            #pragma unroll
            for (int k = 0; k < 8; k++) {
                int cj = __builtin_amdgcn_readlane(c, j0 + k);
                int vb = __builtin_amdgcn_readlane(__float_as_int(v), j0 + k);
                vv[k] = __int_as_float(vb);
                xv[k] = x[(size_t)cj * DFEAT + lane];   // coalesced 256B row
            }
            #pragma unroll
            for (int k = 0; k < 8; k++)
                acc += vv[k] * xv[k];
        }
    }
    out[(size_t)wid * DFEAT + lane] =
        acc + x0[(size_t)wid * DFEAT + lane] + bias[lane];
}

// Phase 3: drain overflow list (small; only rows with degree > C).
__global__ void overflow_drain_kernel(const int* __restrict__ edge_row,
                                      const int* __restrict__ edge_col,
                                      const float* __restrict__ edge_val,
                                      const float* __restrict__ x,
                                      const int* __restrict__ ov_cursor,
                                      const int* __restrict__ ov_list,
                                      float* __restrict__ out, int E) {
    int n = ov_cursor[0];
    if (n > E) n = E;
    int wid = (blockIdx.x * blockDim.x + threadIdx.x) >> 6;
    int lane = threadIdx.x & 63;
    int nw = (gridDim.x * blockDim.x) >> 6;
    for (int k = wid; k < n; k += nw) {
        int e = ov_list[k];
        int r = edge_row[e], c = edge_col[e];
        float v = edge_val[e];
        atomicAdd(&out[(size_t)r * DFEAT + lane],
                  v * x[(size_t)c * DFEAT + lane]);
    }
}

// ---------- fallback path (round-1 structure; used only if ws too small) ----------
__global__ void init_out_kernel(const float* __restrict__ x0,
                                const float* __restrict__ bias,
                                float* __restrict__ out, int n4) {
    int i = blockIdx.x * blockDim.x + threadIdx.x;
    if (i < n4) {
        float4 v = ((const float4*)x0)[i];
        int d = (i * 4) & (DFEAT - 1);
        v.x += bias[d + 0]; v.y += bias[d + 1];
        v.z += bias[d + 2]; v.w += bias[d + 3];
        ((float4*)out)[i] = v;
    }
}

__global__ void edge_scatter_kernel(const float* __restrict__ x,
                                    const float* __restrict__ edge_val,
                                    const int* __restrict__ edge_row,
                                    const int* __restrict__ edge_col,
                                    float* __restrict__ out, int E) {
    int tid = blockIdx.x * blockDim.x + threadIdx.x;
    int wave = tid >> 6, lane = tid & 63;
    int nwaves = (gridDim.x * blockDim.x) >> 6;
    for (int e = wave; e < E; e += nwaves) {
        int row = edge_row[e];
        int col = edge_col[e];
        float val = edge_val[e];
        atomicAdd(&out[row * DFEAT + lane], val * x[col * DFEAT + lane]);
    }
}

extern "C" void kernel_launch(void* const* d_in, const int* in_sizes, int n_in,
                              void* d_out, int out_size, void* d_ws, size_t ws_size,
                              hipStream_t stream) {
    const float* x    = (const float*)d_in[0];
    const float* x0   = (const float*)d_in[1];
    const float* ev   = (const float*)d_in[2];
    // d_in[3] = weight: unused (Cayley == identity)
    const float* bias = (const float*)d_in[4];
    const int*   er   = (const int*)d_in[5];
    const int*   ec   = (const int*)d_in[6];
    float* out = (float*)d_out;

    int E = in_sizes[2];
    int N = out_size / DFEAT;

    // workspace layout: [cursor N][ov_cursor][ov_list E][bucket N*C int2]
    size_t cur_bytes = (((size_t)N * 4) + 255) & ~size_t(255);
    size_t ovc_bytes = 256;
    size_t ov_bytes  = (((size_t)E * 4) + 255) & ~size_t(255);
    size_t fixed     = cur_bytes + ovc_bytes + ov_bytes;

    // Largest capacity that fits (degree is ~Poisson(E/N); C>=28 keeps the
    // overflow drain tiny for avg degree 16).
    int C = 0;
    if (ws_size > fixed) {
        long long cmax = (long long)((ws_size - fixed) / ((size_t)N * 8));
        for (int cand : {64, 48, 40, 32, 28, 24}) {
            if (cmax >= cand) { C = cand; break; }
        }
    }

    if (C >= 24) {
        char* ws = (char*)d_ws;
        int*  cursor  = (int*)ws;
        int*  ovc     = (int*)(ws + cur_bytes);
        int*  ov_list = (int*)(ws + cur_bytes + ovc_bytes);
        int2* bucket  = (int2*)(ws + fixed);

        hipMemsetAsync(cursor, 0, cur_bytes + ovc_bytes, stream);
        bucket_scatter_kernel<<<(E + 255) / 256, 256, 0, stream>>>(
            er, ec, ev, cursor, bucket, ovc, ov_list, E, C);
        int blocks = (N * 64 + 255) / 256;   // one wave per row
        spmm_kernel<<<blocks, 256, 0, stream>>>(
            x, x0, bias, cursor, bucket, out, N, C);
        overflow_drain_kernel<<<64, 256, 0, stream>>>(
            er, ec, ev, x, ovc, ov_list, out, E);
    } else {
        // fallback: atomic-scatter path (correct at any ws)
        int n4 = out_size / 4;
        init_out_kernel<<<(n4 + 255) / 256, 256, 0, stream>>>(x0, bias, out, n4);
        edge_scatter_kernel<<<8192, 256, 0, stream>>>(x, ev, er, ec, out, E);
    }
}

// Round 8
// 182.963 us; speedup vs baseline: 2.9173x; 1.0382x over previous
//
#include <hip/hip_runtime.h>

// GraphConvolution: out = segment_sum(edge_val * x[edge_col], edge_row) + x_0 + bias
// (Cayley transform in the reference is exactly identity => support == x.)
//
// Round 8: two-phase locality-preserving bucket build + R7 register spmm.
//   Phase A: entry=int2{(row<<16)|col, val} appended to (partition, XCC) shard
//     lists. One XCD owns each frontier -> its L2 fills 64B lines with 8
//     entries before write-back (kills the 64B-per-8B-store amplification).
//   Phase B: one block per 64-row partition; reads shard lists coalesced,
//     claims per-row slots with native LDS *integer* atomics (ds_add_u32;
//     the R5/R6 poison was LDS *float* atomicAdd), writes bucket[row*C+pos].
//     Partition bucket region (16KB) is written by one block -> L2-coalesced.
//   Phase C: R7 spmm (wave/row, readlane-batched MLP=8 gathers, register acc,
//     fused out = acc + x0 + bias).
//   Overflow (shard cap or row cap): int2 entry pushed to ov_list of capacity
//     E (an edge contributes at most one overflow entry -> cannot drop).
//     Drained AFTER spmm with HW global f32 atomics. Correct for any caps.

#define DFEAT 64
#define RPB   64            // rows per partition (and per R5-style bin)
#define NSH   8             // shards per partition (one per XCD)

__device__ __forceinline__ unsigned get_xcc_id() {
    unsigned v;
    asm volatile("s_getreg_b32 %0, hwreg(HW_REG_XCC_ID, 0, 32)" : "=s"(v));
    return v & 7u;
}

// ---------------- two-phase path (requires N <= 65536, N % RPB == 0) --------

// Phase A: one thread per edge; append payload to (partition, xcc) shard.
__global__ void partition_scatter_kernel(const int* __restrict__ edge_row,
                                         const int* __restrict__ edge_col,
                                         const float* __restrict__ edge_val,
                                         int* __restrict__ scursor,
                                         int2* __restrict__ slists,
                                         int* __restrict__ ov_cursor,
                                         int2* __restrict__ ov_list,
                                         int E, int scap) {
    int e = blockIdx.x * blockDim.x + threadIdx.x;
    if (e >= E) return;
    int r = edge_row[e];
    int2 ent;
    ent.x = (int)(((unsigned)r << 16) | (unsigned)edge_col[e]);
    ent.y = __float_as_int(edge_val[e]);
    int sidx = ((r >> 6) << 3) | (int)get_xcc_id();
    int pos = atomicAdd(&scursor[sidx], 1);
    if (pos < scap) {
        slists[(size_t)sidx * scap + pos] = ent;
    } else {
        int op = atomicAdd(ov_cursor, 1);
        ov_list[op] = ent;            // ov capacity == E: cannot overflow
    }
}

// Phase B: one block per partition; LDS int cursors; bucket stores stay in
// this block's XCD L2 (16KB region) -> write-back is payload-granular.
__global__ __launch_bounds__(256) void bucket_build_kernel(
        const int* __restrict__ scursor,
        const int2* __restrict__ slists,
        int* __restrict__ counts,
        int2* __restrict__ bucket,
        int* __restrict__ ov_cursor,
        int2* __restrict__ ov_list,
        int scap, int C) {
    __shared__ int cur[RPB];
    int p = blockIdx.x;
    int t = threadIdx.x;
    if (t < RPB) cur[t] = 0;
    __syncthreads();
    for (int s = 0; s < NSH; s++) {
        int sidx = (p << 3) | s;
        int cnt = scursor[sidx];
        if (cnt > scap) cnt = scap;   // beyond-cap entries already in ov_list
        const int2* list = slists + (size_t)sidx * scap;
        for (int i = t; i < cnt; i += 256) {
            int2 ent = list[i];
            int row = (int)((unsigned)ent.x >> 16);
            int pos = atomicAdd(&cur[row & (RPB - 1)], 1);   // ds_add_u32
            if (pos < C) {
                bucket[(size_t)row * C + pos] = ent;
            } else {
                int op = atomicAdd(ov_cursor, 1);
                ov_list[op] = ent;    // total pushes across A+B <= E
            }
        }
    }
    __syncthreads();
    if (t < RPB) {
        int c = cur[t];
        counts[p * RPB + t] = (c < C) ? c : C;
    }
}

// Phase C: one 64-lane wave per row; lane d owns feature d.
// Register accumulator; 8 independent coalesced 256B gathers in flight.
__global__ __launch_bounds__(256) void spmm_kernel(
        const float* __restrict__ x,
        const float* __restrict__ x0,
        const float* __restrict__ bias,
        const int* __restrict__ counts,
        const int2* __restrict__ bucket,
        float* __restrict__ out, int n, int C, int cmask) {
    int wid = (blockIdx.x * blockDim.x + threadIdx.x) >> 6;
    int lane = threadIdx.x & 63;
    if (wid >= n) return;
    int cnt = counts[wid];
    if (cnt > C) cnt = C;
    const int2* bk = bucket + (size_t)wid * C;
    float acc = 0.f;
    for (int s0 = 0; s0 < cnt; s0 += 64) {
        int m = cnt - s0; if (m > 64) m = 64;
        int c = 0; float v = 0.f;      // padding lanes: col 0, val 0 -> adds 0
        if (lane < m) {
            int2 p = bk[s0 + lane];    // coalesced: row bucket is contiguous
            c = p.x & cmask;
            v = __int_as_float(p.y);
        }
        for (int j0 = 0; j0 < m; j0 += 8) {
            float xv[8], vv[8];
            #pragma unroll
            for (int k = 0; k < 8; k++) {
                int cj = __builtin_amdgcn_readlane(c, j0 + k);
                int vb = __builtin_amdgcn_readlane(__float_as_int(v), j0 + k);
                vv[k] = __int_as_float(vb);
                xv[k] = x[(size_t)cj * DFEAT + lane];   // coalesced 256B row
            }
            #pragma unroll
            for (int k = 0; k < 8; k++)
                acc += vv[k] * xv[k];
        }
    }
    out[(size_t)wid * DFEAT + lane] =
        acc + x0[(size_t)wid * DFEAT + lane] + bias[lane];
}

// Drain packed int2 overflow entries (normally ~empty). Runs AFTER spmm.
__global__ void ov_drain_packed_kernel(const float* __restrict__ x,
                                       const int* __restrict__ ov_cursor,
                                       const int2* __restrict__ ov_list,
                                       float* __restrict__ out, int cap) {
    int n = ov_cursor[0];
    if (n > cap) n = cap;
    int wid = (blockIdx.x * blockDim.x + threadIdx.x) >> 6;
    int lane = threadIdx.x & 63;
    int nw = (gridDim.x * blockDim.x) >> 6;
    for (int k = wid; k < n; k += nw) {
        int2 p = ov_list[k];
        unsigned ux = (unsigned)p.x;
        int r = (int)(ux >> 16);
        int c = (int)(ux & 0xFFFFu);
        float v = __int_as_float(p.y);
        atomicAdd(&out[(size_t)r * DFEAT + lane],
                  v * x[(size_t)c * DFEAT + lane]);
    }
}

// ---------------- R7 single-phase path (general N; medium ws) ---------------

__global__ void bucket_scatter_kernel(const int* __restrict__ edge_row,
                                      const int* __restrict__ edge_col,
                                      const float* __restrict__ edge_val,
                                      int* __restrict__ cursor,
                                      int2* __restrict__ bucket,
                                      int* __restrict__ ov_cursor,
                                      int* __restrict__ ov_list,
                                      int E, int C) {
    int e = blockIdx.x * blockDim.x + threadIdx.x;
    if (e >= E) return;
    int r = edge_row[e];
    int pos = atomicAdd(&cursor[r], 1);
    if (pos < C) {
        int2 ent;
        ent.x = edge_col[e];
        ent.y = __float_as_int(edge_val[e]);
        bucket[(size_t)r * C + pos] = ent;
    } else {
        int op = atomicAdd(ov_cursor, 1);
        ov_list[op] = e;               // capacity E: cannot overflow
    }
}

__global__ void ov_drain_id_kernel(const int* __restrict__ edge_row,
                                   const int* __restrict__ edge_col,
                                   const float* __restrict__ edge_val,
                                   const float* __restrict__ x,
                                   const int* __restrict__ ov_cursor,
                                   const int* __restrict__ ov_list,
                                   float* __restrict__ out, int E) {
    int n = ov_cursor[0];
    if (n > E) n = E;
    int wid = (blockIdx.x * blockDim.x + threadIdx.x) >> 6;
    int lane = threadIdx.x & 63;
    int nw = (gridDim.x * blockDim.x) >> 6;
    for (int k = wid; k < n; k += nw) {
        int e = ov_list[k];
        int r = edge_row[e], c = edge_col[e];
        float v = edge_val[e];
        atomicAdd(&out[(size_t)r * DFEAT + lane],
                  v * x[(size_t)c * DFEAT + lane]);
    }
}

// ---------------- last-resort fallback (round-1 structure) ------------------

__global__ void init_out_kernel(const float* __restrict__ x0,
                                const float* __restrict__ bias,
                                float* __restrict__ out, int n4) {
    int i = blockIdx.x * blockDim.x + threadIdx.x;
    if (i < n4) {
        float4 v = ((const float4*)x0)[i];
        int d = (i * 4) & (DFEAT - 1);
        v.x += bias[d + 0]; v.y += bias[d + 1];
        v.z += bias[d + 2]; v.w += bias[d + 3];
        ((float4*)out)[i] = v;
    }
}

__global__ void edge_scatter_kernel(const float* __restrict__ x,
                                    const float* __restrict__ edge_val,
                                    const int* __restrict__ edge_row,
                                    const int* __restrict__ edge_col,
                                    float* __restrict__ out, int E) {
    int tid = blockIdx.x * blockDim.x + threadIdx.x;
    int wave = tid >> 6, lane = tid & 63;
    int nwaves = (gridDim.x * blockDim.x) >> 6;
    for (int e = wave; e < E; e += nwaves) {
        int row = edge_row[e];
        int col = edge_col[e];
        float val = edge_val[e];
        atomicAdd(&out[row * DFEAT + lane], val * x[col * DFEAT + lane]);
    }
}

extern "C" void kernel_launch(void* const* d_in, const int* in_sizes, int n_in,
                              void* d_out, int out_size, void* d_ws, size_t ws_size,
                              hipStream_t stream) {
    const float* x    = (const float*)d_in[0];
    const float* x0   = (const float*)d_in[1];
    const float* ev   = (const float*)d_in[2];
    // d_in[3] = weight: unused (Cayley == identity)
    const float* bias = (const float*)d_in[4];
    const int*   er   = (const int*)d_in[5];
    const int*   ec   = (const int*)d_in[6];
    float* out = (float*)d_out;

    int E = in_sizes[2];
    int N = out_size / DFEAT;

    auto align256 = [](size_t b) { return (b + 255) & ~size_t(255); };

    // ---- try two-phase path ----
    if (N <= 65536 && N % RPB == 0 && E > 0) {
        int NP = N / RPB;                       // partitions (1024)
        size_t nshard = (size_t)NP * NSH;

        size_t scur_b  = align256(nshard * 4);
        size_t cnts_b  = align256((size_t)N * 4);
        size_t ovc_b   = 256;
        size_t ov_b    = align256((size_t)E * 8);   // int2, capacity E
        size_t fixed   = scur_b + cnts_b + ovc_b + ov_b;

        struct Cfg { int scap, C; };
        const Cfg cfgs[] = {{256, 32}, {192, 32}, {192, 24}, {160, 24}, {128, 24}};
        int scap = 0, C = 0;
        size_t sl_b = 0, bk_b = 0;
        for (const Cfg& cf : cfgs) {
            size_t s = align256(nshard * (size_t)cf.scap * 8);
            size_t b = align256((size_t)N * (size_t)cf.C * 8);
            if (fixed + s + b <= ws_size) { scap = cf.scap; C = cf.C; sl_b = s; bk_b = b; break; }
        }
        if (C > 0) {
            char* ws = (char*)d_ws;
            int*  scursor = (int*)ws;
            int*  counts  = (int*)(ws + scur_b);
            int*  ovc     = (int*)(ws + scur_b + cnts_b);
            int2* ov_list = (int2*)(ws + scur_b + cnts_b + ovc_b);
            int2* slists  = (int2*)(ws + fixed);
            int2* bucket  = (int2*)(ws + fixed + sl_b);

            hipMemsetAsync(scursor, 0, scur_b, stream);
            hipMemsetAsync(ovc, 0, ovc_b, stream);
            partition_scatter_kernel<<<(E + 255) / 256, 256, 0, stream>>>(
                er, ec, ev, scursor, slists, ovc, ov_list, E, scap);
            bucket_build_kernel<<<NP, 256, 0, stream>>>(
                scursor, slists, counts, bucket, ovc, ov_list, scap, C);
            int blocks = (N * 64 + 255) / 256;   // one wave per row
            spmm_kernel<<<blocks, 256, 0, stream>>>(
                x, x0, bias, counts, bucket, out, N, C, 0xFFFF);
            ov_drain_packed_kernel<<<64, 256, 0, stream>>>(
                x, ovc, ov_list, out, E);
            return;
        }
    }

    // ---- R7 single-phase path ----
    {
        size_t cur_b = align256((size_t)N * 4);
        size_t ovc_b = 256;
        size_t ov_b  = align256((size_t)E * 4);
        size_t fixed = cur_b + ovc_b + ov_b;
        int C = 0;
        if (ws_size > fixed) {
            long long cmax = (long long)((ws_size - fixed) / ((size_t)N * 8));
            for (int cand : {64, 48, 40, 32, 28, 24})
                if (cmax >= cand) { C = cand; break; }
        }
        if (C >= 24) {
            char* ws = (char*)d_ws;
            int*  cursor  = (int*)ws;
            int*  ovc     = (int*)(ws + cur_b);
            int*  ov_list = (int*)(ws + cur_b + ovc_b);
            int2* bucket  = (int2*)(ws + fixed);

            hipMemsetAsync(cursor, 0, cur_b + ovc_b, stream);
            bucket_scatter_kernel<<<(E + 255) / 256, 256, 0, stream>>>(
                er, ec, ev, cursor, bucket, ovc, ov_list, E, C);
            int blocks = (N * 64 + 255) / 256;
            spmm_kernel<<<blocks, 256, 0, stream>>>(
                x, x0, bias, cursor, bucket, out, N, C, -1);
            ov_drain_id_kernel<<<64, 256, 0, stream>>>(
                er, ec, ev, x, ovc, ov_list, out, E);
            return;
        }
    }

    // ---- last resort: atomic scatter ----
    int n4 = out_size / 4;
    init_out_kernel<<<(n4 + 255) / 256, 256, 0, stream>>>(x0, bias, out, n4);
    edge_scatter_kernel<<<8192, 256, 0, stream>>>(x, ev, er, ec, out, E);
}